// Round 4
// baseline (679.111 us; speedup 1.0000x reference)
//
#include <hip/hip_runtime.h>
#include <math.h>

// CRITICAL: no FMA contraction — bit-replicating numpy's SSE float32 einsum.
#pragma clang fp contract(off)

typedef float f32x2 __attribute__((ext_vector_type(2)));

#define T_TOKENS 16384
#define HDIM 2048
#define NEXP 64
#define TOPK 6
#define SEQ 4096
#define TPB 32          // tokens per block
#define NTHR 128        // 2 waves
#define KC 64           // k-chunk
#define WS 68           // padded LDS stride for W tile (2-way conflicts = free)
#define LGS 65          // padded stride for logits/probs scratch

// numpy chain lanes {2h,2h+1} as one packed-fp32 pair:
// acc = a*b + acc with separate v_pk_mul / v_pk_add (IEEE RN each, no FMA),
// applied j=3..0 reproduces v = a0b0 + (a1b1 + (a2b2 + (a3b3 + v))) exactly.
__device__ __forceinline__ void pk_macc(f32x2 &acc, f32x2 a, f32x2 b) {
    f32x2 p, r;
    asm("v_pk_mul_f32 %0, %1, %2" : "=v"(p) : "v"(a), "v"(b));
    asm("v_pk_add_f32 %0, %1, %2" : "=v"(r) : "v"(p), "v"(acc));
    acc = r;
}

// Thread layout (128 thr): le = tid&15 -> experts {le,le+16,le+32,le+48}
//   h = (tid>>4)&1 -> numpy chain lanes {2h, 2h+1}
//   tg = tid>>5 (0..3) -> tokens tg*8 .. tg*8+7
__global__ __launch_bounds__(NTHR, 2) void moe_gate_main(
    const float* __restrict__ x, const float* __restrict__ wgt,
    float* __restrict__ out, float* __restrict__ gacc)
{
    __shared__ float w_lds[NEXP * WS];   // 17408 B; epilogue lg+part1 alias here
    __shared__ float psum[2 * NEXP];
    __shared__ int   cnt[NEXP];

    const int tid = threadIdx.x;
    const int bid = blockIdx.x;
    const int tb  = bid * TPB;
    const int b   = tb >> 12;            // /4096

    const int le = tid & 15;
    const int h  = (tid >> 4) & 1;
    const int tg = tid >> 5;
    const int t0 = tg * 8;

    f32x2 acc[4][8];                     // [expert je][token tt], 64 VGPRs
    #pragma unroll
    for (int je = 0; je < 4; ++je)
        #pragma unroll
        for (int tt = 0; tt < 8; ++tt) { acc[je][tt].x = 0.f; acc[je][tt].y = 0.f; }

    const float* xbase = x + (size_t)(tb + t0) * HDIM + 2 * h;

    for (int c = 0; c < HDIM / KC; ++c) {
        const int k0 = c * KC;
        // ---- stage W chunk: 64 rows x 16 float4, 8 f4/thread, coalesced
        #pragma unroll
        for (int i = 0; i < 8; ++i) {
            int idx = i * NTHR + tid;
            int e = idx >> 4, c4 = idx & 15;
            float4 v = *reinterpret_cast<const float4*>(&wgt[e * HDIM + k0 + c4 * 4]);
            *reinterpret_cast<float4*>(&w_lds[e * WS + c4 * 4]) = v;
        }
        __syncthreads();

        #pragma unroll
        for (int b16 = 0; b16 < 4; ++b16) {
            const int lb = b16 * 16;
            // x fragments direct from global (L1-coalesced; never staged in LDS)
            f32x2 xa[8][4];
            #pragma unroll
            for (int tt = 0; tt < 8; ++tt)
                #pragma unroll
                for (int j = 0; j < 4; ++j)
                    xa[tt][j] = *reinterpret_cast<const f32x2*>(
                        &xbase[(size_t)tt * HDIM + k0 + lb + j * 4]);
            // j descending == numpy's reversed muladd chain
            #pragma unroll
            for (int j = 3; j >= 0; --j) {
                f32x2 wf[4];
                #pragma unroll
                for (int je = 0; je < 4; ++je)
                    wf[je] = *reinterpret_cast<const f32x2*>(
                        &w_lds[(le + 16 * je) * WS + lb + j * 4 + 2 * h]);
                #pragma unroll
                for (int je = 0; je < 4; ++je)
                    #pragma unroll
                    for (int tt = 0; tt < 8; ++tt)
                        pk_macc(acc[je][tt], wf[je], xa[tt][j]);
            }
        }
        __syncthreads();
    }

    // ---- combine chain halves: S = (v0+v1) + (v2+v3), split h0 + h1
    float* lg    = w_lds;                // [32][65]
    float* part1 = w_lds + TPB * LGS;    // [32][65]

    if (h == 1) {
        #pragma unroll
        for (int je = 0; je < 4; ++je)
            #pragma unroll
            for (int tt = 0; tt < 8; ++tt)
                part1[(t0 + tt) * LGS + le + 16 * je] = acc[je][tt].x + acc[je][tt].y;
    }
    if (tid < NEXP) cnt[tid] = 0;
    __syncthreads();
    if (h == 0) {
        #pragma unroll
        for (int je = 0; je < 4; ++je)
            #pragma unroll
            for (int tt = 0; tt < 8; ++tt) {
                float p0 = acc[je][tt].x + acc[je][tt].y;
                lg[(t0 + tt) * LGS + le + 16 * je] =
                    p0 + part1[(t0 + tt) * LGS + le + 16 * je];
            }
    }
    __syncthreads();

    // ---- softmax per token (threads 0..31), in place, numpy pairwise sum
    if (tid < TPB) {
        const int t = tid;
        float mx = lg[t * LGS];
        for (int e = 1; e < NEXP; ++e) { float v = lg[t * LGS + e]; if (v > mx) mx = v; }
        for (int e = 0; e < NEXP; ++e)
            lg[t * LGS + e] = expf(lg[t * LGS + e] - mx);
        float r[8];
        #pragma unroll
        for (int j = 0; j < 8; ++j) r[j] = lg[t * LGS + j];
        for (int i = 8; i < 64; i += 8)
            #pragma unroll
            for (int j = 0; j < 8; ++j) r[j] += lg[t * LGS + i + j];
        float S = ((r[0] + r[1]) + (r[2] + r[3])) + ((r[4] + r[5]) + (r[6] + r[7]));
        for (int e = 0; e < NEXP; ++e) lg[t * LGS + e] = lg[t * LGS + e] / S;
    }
    __syncthreads();

    // ---- partial per-expert prob sums (aux loss), all 128 threads
    {
        const int e = tid & 63, q = tid >> 6;
        float s = 0.f;
        for (int t = q * 16; t < q * 16 + 16; ++t) s += lg[t * LGS + e];
        psum[q * 64 + e] = s;
    }
    __syncthreads();

    if (tid < TPB) {
        // ---- top-6 on probs, strict > ascending scan (tie -> lowest index)
        const int t = tid;
        const int gt = tb + t;
        float pv[TOPK]; int pi[TOPK];
        for (int r = 0; r < TOPK; ++r) {
            float bv = -1.f; int be = 0;
            for (int e = 0; e < NEXP; ++e) {
                float v = lg[t * LGS + e];
                if (v > bv) { bv = v; be = e; }
            }
            lg[t * LGS + be] = -1.f;
            pv[r] = bv; pi[r] = be;
            atomicAdd(&cnt[be], 1);
        }
        float wsum = pv[0];
        #pragma unroll
        for (int r = 1; r < TOPK; ++r) wsum += pv[r];
        wsum += 1e-20f;
        #pragma unroll
        for (int r = 0; r < TOPK; ++r) {
            out[(size_t)gt * TOPK + r] = (float)pi[r];
            out[(size_t)T_TOKENS * TOPK + (size_t)gt * TOPK + r] = pv[r] / wsum;
        }
    } else if (tid >= 64 && tid < 128) {
        const int e = tid - 64;
        atomicAdd(&gacc[b * 64 + e], psum[e] + psum[64 + e]);
    }
    __syncthreads();
    if (tid < NEXP) {
        atomicAdd(&gacc[256 + b * 64 + tid], (float)cnt[tid]);
    }
}

// Finalize: aux = ALPHA * mean_b( sum_e (cnt*E/(S*K)) * (ssum/S) )
__global__ __launch_bounds__(256) void moe_gate_aux(
    const float* __restrict__ gacc, float* __restrict__ out)
{
    __shared__ float red[4];
    const int tid = threadIdx.x;
    float v = gacc[256 + tid] * gacc[tid];
    #pragma unroll
    for (int o = 32; o > 0; o >>= 1) v += __shfl_down(v, o, 64);
    if ((tid & 63) == 0) red[tid >> 6] = v;
    __syncthreads();
    if (tid == 0) {
        float tot = red[0] + red[1] + red[2] + red[3];
        const float scale = (64.0f / (4096.0f * 6.0f)) / 4096.0f;
        out[2 * T_TOKENS * TOPK] = 1e-3f * (tot * scale) * 0.25f;
    }
}

extern "C" void kernel_launch(void* const* d_in, const int* in_sizes, int n_in,
                              void* d_out, int out_size, void* d_ws, size_t ws_size,
                              hipStream_t stream) {
    const float* x   = (const float*)d_in[0];
    const float* wgt = (const float*)d_in[1];
    float* out  = (float*)d_out;
    float* gacc = (float*)d_ws;

    hipMemsetAsync(d_ws, 0, 512 * sizeof(float), stream);
    moe_gate_main<<<T_TOKENS / TPB, NTHR, 0, stream>>>(x, wgt, out, gacc);
    moe_gate_aux<<<1, 256, 0, stream>>>(gacc, out);
}

// Round 5
// 350.223 us; speedup vs baseline: 1.9391x; 1.9391x over previous
//
#include <hip/hip_runtime.h>
#include <math.h>

// CRITICAL: no FMA contraction — bit-replicating numpy's SSE float32 einsum.
#pragma clang fp contract(off)

typedef float f32x2 __attribute__((ext_vector_type(2)));

#define T_TOKENS 16384
#define HDIM 2048
#define NEXP 64
#define TOPK 6
#define SEQ 4096
#define TPB 32          // tokens per block
#define NTHR 256        // 4 waves
#define KC 64           // k-chunk
#define WS 68           // padded LDS stride for W tile (proven ~free in round 3)
#define LGS 65          // padded stride for logits/probs scratch

// One packed step of numpy's reversed muladd chain: acc = a*b + acc with
// SEPARATE v_pk_mul / v_pk_add (IEEE RN each, no FMA). Packing SSE chain
// lanes {0,1} and {2,3} into f32x2 is bit-exact per lane.
__device__ __forceinline__ void pk_macc(f32x2 &acc, f32x2 a, f32x2 b) {
    f32x2 p, r;
    asm("v_pk_mul_f32 %0, %1, %2" : "=v"(p) : "v"(a), "v"(b));
    asm("v_pk_add_f32 %0, %1, %2" : "=v"(r) : "v"(p), "v"(acc));
    acc = r;
}

__device__ __forceinline__ f32x2 lo2(const float4& v) { f32x2 r; r.x = v.x; r.y = v.y; return r; }
__device__ __forceinline__ f32x2 hi2(const float4& v) { f32x2 r; r.x = v.z; r.y = v.w; return r; }

// Thread layout (256 thr): le = tid&15 -> experts {le,le+16,le+32,le+48}
//   grp = tid>>4 (0..15) -> tokens grp*2, grp*2+1
__global__ __launch_bounds__(NTHR, 2) void moe_gate_main(
    const float* __restrict__ x, const float* __restrict__ wgt,
    float* __restrict__ out, float* __restrict__ gacc)
{
    __shared__ float w_lds[NEXP * WS];    // 17408 B (W chunk only)
    __shared__ float lg[TPB * LGS];       //  8320 B
    __shared__ float probs[TPB * LGS];    //  8320 B
    __shared__ float psum[4 * NEXP];      //  1024 B
    __shared__ int   cnt[NEXP];           //   256 B

    const int tid = threadIdx.x;
    const int bid = blockIdx.x;
    const int tb  = bid * TPB;
    const int b   = tb >> 12;             // /4096

    const int le    = tid & 15;
    const int grp   = tid >> 4;           // 0..15
    const int trow0 = grp * 2;

    // accumulators: [expert je][token tt], chains {0,1} and {2,3}
    f32x2 aclo[4][2], achi[4][2];
    #pragma unroll
    for (int je = 0; je < 4; ++je)
        #pragma unroll
        for (int tt = 0; tt < 2; ++tt) {
            aclo[je][tt].x = 0.f; aclo[je][tt].y = 0.f;
            achi[je][tt].x = 0.f; achi[je][tt].y = 0.f;
        }

    const float* xr0 = x + (size_t)(tb + trow0) * HDIM;
    const float* xr1 = xr0 + HDIM;

    // W staging indices (constant over chunks): row i*16+grp, cols le*4..le*4+3
    // Global read coalesced (lanes le consecutive float4s); LDS pattern = round 3's.
    float4 wstg[4];
    #pragma unroll
    for (int i = 0; i < 4; ++i)
        wstg[i] = *reinterpret_cast<const float4*>(&wgt[(i * 16 + grp) * HDIM + le * 4]);

    for (int c = 0; c < HDIM / KC; ++c) {
        const int k0 = c * KC;
        __syncthreads();   // previous chunk's readers done
        #pragma unroll
        for (int i = 0; i < 4; ++i)
            *reinterpret_cast<float4*>(&w_lds[(i * 16 + grp) * WS + le * 4]) = wstg[i];
        __syncthreads();
        // issue next chunk's W loads now; consumed at next iteration's ds_write
        if (c < HDIM / KC - 1) {
            const int kn = k0 + KC;
            #pragma unroll
            for (int i = 0; i < 4; ++i)
                wstg[i] = *reinterpret_cast<const float4*>(&wgt[(i * 16 + grp) * HDIM + kn + le * 4]);
        }

        // x fragments for b16=0 (global, L1/HBM; 16 lanes share each address)
        float4 xc[2][4], xn[2][4];
        #pragma unroll
        for (int j = 0; j < 4; ++j) {
            xc[0][j] = *reinterpret_cast<const float4*>(&xr0[k0 + j * 4]);
            xc[1][j] = *reinterpret_cast<const float4*>(&xr1[k0 + j * 4]);
        }

        #pragma unroll
        for (int b16 = 0; b16 < 4; ++b16) {
            const int kk = b16 * 16;
            if (b16 < 3) {
                const int kp = k0 + kk + 16;
                #pragma unroll
                for (int j = 0; j < 4; ++j) {
                    xn[0][j] = *reinterpret_cast<const float4*>(&xr0[kp + j * 4]);
                    xn[1][j] = *reinterpret_cast<const float4*>(&xr1[kp + j * 4]);
                }
            }
            // numpy's reversed chain: j = 3..0, acc = w_j*x_j + acc
            #pragma unroll
            for (int j = 3; j >= 0; --j) {
                f32x2 xl0 = lo2(xc[0][j]), xh0 = hi2(xc[0][j]);
                f32x2 xl1 = lo2(xc[1][j]), xh1 = hi2(xc[1][j]);
                #pragma unroll
                for (int je = 0; je < 4; ++je) {
                    float4 wf = *reinterpret_cast<const float4*>(
                        &w_lds[(le + 16 * je) * WS + kk + j * 4]);
                    f32x2 wl = lo2(wf), wh = hi2(wf);
                    pk_macc(aclo[je][0], wl, xl0);
                    pk_macc(achi[je][0], wh, xh0);
                    pk_macc(aclo[je][1], wl, xl1);
                    pk_macc(achi[je][1], wh, xh1);
                }
            }
            #pragma unroll
            for (int t = 0; t < 2; ++t)
                #pragma unroll
                for (int j = 0; j < 4; ++j) xc[t][j] = xn[t][j];
        }
    }

    // ---- logits: hadd exactly like npyv_sum_f32: (v0+v1)+(v2+v3)
    #pragma unroll
    for (int je = 0; je < 4; ++je)
        #pragma unroll
        for (int tt = 0; tt < 2; ++tt) {
            float v = (aclo[je][tt].x + aclo[je][tt].y) + (achi[je][tt].x + achi[je][tt].y);
            lg[(trow0 + tt) * LGS + le + 16 * je] = v;
        }
    if (tid < NEXP) cnt[tid] = 0;
    __syncthreads();

    // ---- softmax per token (threads 0..31), fp32, numpy pairwise sum
    if (tid < TPB) {
        const int t = tid;
        float mx = lg[t * LGS];
        for (int e = 1; e < NEXP; ++e) { float v = lg[t * LGS + e]; if (v > mx) mx = v; }
        for (int e = 0; e < NEXP; ++e)
            probs[t * LGS + e] = expf(lg[t * LGS + e] - mx);
        float r[8];
        #pragma unroll
        for (int j = 0; j < 8; ++j) r[j] = probs[t * LGS + j];
        for (int i = 8; i < 64; i += 8)
            #pragma unroll
            for (int j = 0; j < 8; ++j) r[j] += probs[t * LGS + i + j];
        float S = ((r[0] + r[1]) + (r[2] + r[3])) + ((r[4] + r[5]) + (r[6] + r[7]));
        for (int e = 0; e < NEXP; ++e) probs[t * LGS + e] = probs[t * LGS + e] / S;
    }
    __syncthreads();

    // ---- partial per-expert prob sums (aux loss), all 256 threads
    {
        const int e = tid & 63, q = tid >> 6;
        float s = 0.f;
        for (int t = q * 8; t < q * 8 + 8; ++t) s += probs[t * LGS + e];
        psum[q * 64 + e] = s;
    }
    __syncthreads();

    if (tid < TPB) {
        // ---- top-6 on probs, strict > ascending scan (tie -> lowest index)
        const int t = tid;
        const int gt = tb + t;
        float pv[TOPK]; int pi[TOPK];
        for (int r = 0; r < TOPK; ++r) {
            float bv = -1.f; int be = 0;
            for (int e = 0; e < NEXP; ++e) {
                float v = probs[t * LGS + e];
                if (v > bv) { bv = v; be = e; }
            }
            probs[t * LGS + be] = -1.f;
            pv[r] = bv; pi[r] = be;
            atomicAdd(&cnt[be], 1);
        }
        float wsum = pv[0];
        #pragma unroll
        for (int r = 1; r < TOPK; ++r) wsum += pv[r];
        wsum += 1e-20f;
        #pragma unroll
        for (int r = 0; r < TOPK; ++r) {
            out[(size_t)gt * TOPK + r] = (float)pi[r];
            out[(size_t)T_TOKENS * TOPK + (size_t)gt * TOPK + r] = pv[r] / wsum;
        }
    } else if (tid >= 64 && tid < 128) {
        const int e = tid - 64;
        float s = psum[e] + psum[64 + e] + psum[128 + e] + psum[192 + e];
        atomicAdd(&gacc[b * 64 + e], s);
    }
    __syncthreads();
    if (tid < NEXP) {
        atomicAdd(&gacc[256 + b * 64 + tid], (float)cnt[tid]);
    }
}

// Finalize: aux = ALPHA * mean_b( sum_e (cnt*E/(S*K)) * (ssum/S) )
__global__ __launch_bounds__(256) void moe_gate_aux(
    const float* __restrict__ gacc, float* __restrict__ out)
{
    __shared__ float red[4];
    const int tid = threadIdx.x;
    float v = gacc[256 + tid] * gacc[tid];
    #pragma unroll
    for (int o = 32; o > 0; o >>= 1) v += __shfl_down(v, o, 64);
    if ((tid & 63) == 0) red[tid >> 6] = v;
    __syncthreads();
    if (tid == 0) {
        float tot = red[0] + red[1] + red[2] + red[3];
        const float scale = (64.0f / (4096.0f * 6.0f)) / 4096.0f;
        out[2 * T_TOKENS * TOPK] = 1e-3f * (tot * scale) * 0.25f;
    }
}

extern "C" void kernel_launch(void* const* d_in, const int* in_sizes, int n_in,
                              void* d_out, int out_size, void* d_ws, size_t ws_size,
                              hipStream_t stream) {
    const float* x   = (const float*)d_in[0];
    const float* wgt = (const float*)d_in[1];
    float* out  = (float*)d_out;
    float* gacc = (float*)d_ws;

    hipMemsetAsync(d_ws, 0, 512 * sizeof(float), stream);
    moe_gate_main<<<T_TOKENS / TPB, NTHR, 0, stream>>>(x, wgt, out, gacc);
    moe_gate_aux<<<1, 256, 0, stream>>>(gacc, out);
}